// Round 8
// baseline (3668.451 us; speedup 1.0000x reference)
//
#include <hip/hip_runtime.h>
#include <cstdint>
#include <cstddef>

#define TT 512
#define BB 64
#define HH 256
#define NG 1024
#define DI 768
#define KY 32

#define PA 776      // A-tile LDS row pitch (bf16 elems): 1552B rows -> 2-way-only aliasing on frag reads
#define PR 276      // ring row pitch (f32): quad offset 16 banks -> 2-way max
#define NW 32       // 32 windows x 16 steps = 512

typedef __attribute__((ext_vector_type(8))) short bfrag_t;
typedef __attribute__((ext_vector_type(4))) float f4_t;

__device__ __forceinline__ float sigf(float x) {
    return __fdividef(1.f, 1.f + __expf(-x));
}
__device__ __forceinline__ float tanhfast(float x) {
    return fmaf(2.f, sigf(2.f * x), -1.f);
}
__device__ __forceinline__ unsigned short bf_hi(float x) {
    return (unsigned short)(__float_as_uint(x) >> 16);        // truncate to bf16
}
__device__ __forceinline__ float bf_hi_f(float x) {
    return __uint_as_float(__float_as_uint(x) & 0xffff0000u); // exact hi part as f32
}

// ---------------------------------------------------------------------------
// kprew: one-time split-bf16 conversion of the B operand, UNSWIZZLED row-major
// [1040][768]: rows 0..1023 = Wih[row][32:800]; rows 1024..1025 = Waff[r][256:1024]
// (the shi columns); rows 1026..1039 = zero padding for the 16-wide shi tile.
// ---------------------------------------------------------------------------
__global__ __launch_bounds__(256) void kprew(
    const float* __restrict__ Wih, const float* __restrict__ Waff,
    unsigned short* __restrict__ Bsh, unsigned short* __restrict__ Bsl)
{
    const int base = (blockIdx.x * 256 + threadIdx.x) * 4;   // 780 blocks cover 1040*768 exactly
    const int row = base / 768;
    const int k = base % 768;
    float4 v;
    if (row < 1024)      v = *(const float4*)(Wih + (size_t)row * 800 + KY + k);
    else if (row < 1026) v = *(const float4*)(Waff + (size_t)(row - 1024) * NG + HH + k);
    else                 v = make_float4(0.f, 0.f, 0.f, 0.f);
    ushort4 h4, l4;
    h4.x = bf_hi(v.x); l4.x = bf_hi(v.x - bf_hi_f(v.x));
    h4.y = bf_hi(v.y); l4.y = bf_hi(v.y - bf_hi_f(v.y));
    h4.z = bf_hi(v.z); l4.z = bf_hi(v.z - bf_hi_f(v.z));
    h4.w = bf_hi(v.w); l4.w = bf_hi(v.w - bf_hi_f(v.w));
    *(ushort4*)&Bsh[base] = h4;
    *(ushort4*)&Bsl[base] = l4;
}

// ---------------------------------------------------------------------------
// init: zero the packed mailbox words (ws is poisoned 0xAA before every run)
// ---------------------------------------------------------------------------
__global__ void kinit(unsigned long long* __restrict__ hbox) {
    hbox[(size_t)blockIdx.x * 512 + threadIdx.x] = 0ull;
}

// ---------------------------------------------------------------------------
// krecg: FUSED recurrence + gate-GEMM. 768 threads:
//   waves 0-7  (tid<512): krec3 recurrence verbatim (proven 1.95us/step),
//                         gates+shi read from the LDS ring instead of global.
//   waves 8-11 (tid>=512): split-bf16 MFMA producing this block's own gate
//                         columns one 16-step window ahead, on the (otherwise
//                         100% idle, MfmaUtil=0) matrix pipe. Schedule is
//                         static: the per-step __syncthreads (all 12 waves)
//                         give producer->consumer ordering with no flags.
// Per window W (16 steps): ws 0-11: 2 K-steps of MFMA for window W+1;
// ws 12: stage A[W+2] (sents rows, f32->split bf16) into the idle A buffer;
// ws 15: ring epilogue (acc -> ring slot (W+1)&1), zero acc.
// Eliminates: gpre HBM round-trip (268MB), kgemm/kshi serial launches.
// ---------------------------------------------------------------------------

#define GEMM_KSTEP(_pb, _k0) do {                                                        \
    const int _ao = gfl * PA + (_k0) + gquad * 8;                                        \
    bfrag_t _ahf = *(const bfrag_t*)&Ah[_pb][_ao];                                       \
    bfrag_t _alf = *(const bfrag_t*)&Al[_pb][_ao];                                       \
    _Pragma("unroll")                                                                    \
    for (int _ni = 0; _ni < 4; ++_ni) {                                                  \
        const size_t _bo = (size_t)(wgi * 256 + g * 64 + _ni * 16 + gfl) * 768           \
                         + (_k0) + gquad * 8;                                            \
        bfrag_t _bhf = *(const bfrag_t*)&Bsh[_bo];                                       \
        bfrag_t _blf = *(const bfrag_t*)&Bsl[_bo];                                       \
        acc[_ni] = __builtin_amdgcn_mfma_f32_16x16x32_bf16(_ahf, _bhf, acc[_ni], 0,0,0); \
        acc[_ni] = __builtin_amdgcn_mfma_f32_16x16x32_bf16(_ahf, _blf, acc[_ni], 0,0,0); \
        acc[_ni] = __builtin_amdgcn_mfma_f32_16x16x32_bf16(_alf, _bhf, acc[_ni], 0,0,0); \
    }                                                                                    \
    if (wgi == 0) {                                                                      \
        const size_t _bo = (size_t)(1024 + gfl) * 768 + (_k0) + gquad * 8;               \
        bfrag_t _bhf = *(const bfrag_t*)&Bsh[_bo];                                       \
        bfrag_t _blf = *(const bfrag_t*)&Bsl[_bo];                                       \
        acc[4] = __builtin_amdgcn_mfma_f32_16x16x32_bf16(_ahf, _bhf, acc[4], 0,0,0);     \
        acc[4] = __builtin_amdgcn_mfma_f32_16x16x32_bf16(_ahf, _blf, acc[4], 0,0,0);     \
        acc[4] = __builtin_amdgcn_mfma_f32_16x16x32_bf16(_alf, _bhf, acc[4], 0,0,0);     \
    }                                                                                    \
} while (0)

#define STAGE_A(_pb2, _tbase) do {                                                       \
    const int _r = gtid >> 4, _c = gtid & 15;                                            \
    const float* _as = sents + ((size_t)b * TT + (_tbase) + _r) * DI + _c * 48;          \
    _Pragma("unroll")                                                                    \
    for (int _i = 0; _i < 12; ++_i) {                                                    \
        float4 _v = *(const float4*)(_as + _i * 4);                                      \
        ushort4 _h4, _l4;                                                                \
        _h4.x = bf_hi(_v.x); _l4.x = bf_hi(_v.x - bf_hi_f(_v.x));                        \
        _h4.y = bf_hi(_v.y); _l4.y = bf_hi(_v.y - bf_hi_f(_v.y));                        \
        _h4.z = bf_hi(_v.z); _l4.z = bf_hi(_v.z - bf_hi_f(_v.z));                        \
        _h4.w = bf_hi(_v.w); _l4.w = bf_hi(_v.w - bf_hi_f(_v.w));                        \
        *(ushort4*)&Ah[_pb2][_r * PA + _c * 48 + _i * 4] = _h4;                          \
        *(ushort4*)&Al[_pb2][_r * PA + _c * 48 + _i * 4] = _l4;                          \
    }                                                                                    \
} while (0)

#define RING_EPI(_rs2) do {                                                              \
    _Pragma("unroll")                                                                    \
    for (int _ni = 0; _ni < 4; ++_ni)                                                    \
        _Pragma("unroll")                                                                \
        for (int _r2 = 0; _r2 < 4; ++_r2)                                                \
            ring[_rs2][(gquad * 4 + _r2) * PR + wgi * 64 + _ni * 16 + gfl] = acc[_ni][_r2]; \
    if (wgi == 0) {                                                                      \
        _Pragma("unroll")                                                                \
        for (int _r2 = 0; _r2 < 4; ++_r2)                                                \
            ring[_rs2][(gquad * 4 + _r2) * PR + 256 + gfl] = acc[4][_r2];                \
    }                                                                                    \
    _Pragma("unroll")                                                                    \
    for (int _i = 0; _i < 5; ++_i) acc[_i] = (f4_t)0.f;                                  \
} while (0)

__global__ __launch_bounds__(768, 3) void krecg(
    const float* __restrict__ sents,            // [64][512][768]
    const unsigned short* __restrict__ Bsh,     // [1040][768]
    const unsigned short* __restrict__ Bsl,
    const float* __restrict__ Whh,              // [1024][256]
    const float* __restrict__ mask,             // [64][512]
    const float* __restrict__ bih, const float* __restrict__ bhh,
    const float* __restrict__ baff,
    float* __restrict__ out,                    // [64][512][2]
    unsigned long long* __restrict__ hbox,      // [2][64][4][64]
    const float* __restrict__ Wih, const float* __restrict__ tag,
    const float* __restrict__ Waff)
{
    const int blk = blockIdx.x;
    const int g = blk >> 6, b = blk & 63;
    const int tid = threadIdx.x;

    __shared__ unsigned short Ah[2][16 * PA];   // 49,664 B
    __shared__ unsigned short Al[2][16 * PA];   // 49,664 B
    __shared__ float ring[2][16 * PR];          // 35,328 B
    __shared__ float hk[8 * 36];
    __shared__ float hnS[HH];
    __shared__ float P[2][4][64];
    __shared__ float tg[2][KY];
    __shared__ float red[8][2];

    // recurrence-role indices (tid<512)
    const int w = tid >> 6, lane = tid & 63;
    const int jl = lane & 7, kq = lane >> 3;
    const int jh = w * 8 + jl;
    const int jglob = g * 64 + jh;
    const int sdim = w * 32 + (lane & 31);
    const int stag = lane >> 5;
    // GEMM-role indices (tid>=512)
    const int gtid = tid - 512;
    const int wgi = (gtid >> 6) & 3, glane = gtid & 63;
    const int gfl = glane & 15, gquad = glane >> 4;

    f4_t acc[5];
#pragma unroll
    for (int i = 0; i < 5; ++i) acc[i] = (f4_t)0.f;

    // recurrence constants
    float4 wreg[4][8];
    float bia0 = 0.f, bia1 = 0.f, bia2 = 0.f, bia3 = 0.f;
    float bf0v = 0.f, bf1v = 0.f, waffR = 0.f, cmi = 0.f, creg = 0.f;
    int pred = -1;
    if (tid < 512) {
#pragma unroll
        for (int gt = 0; gt < 4; ++gt) {
            const float4* src = (const float4*)(Whh + (size_t)(gt * HH + jglob) * HH + kq * 32);
#pragma unroll
            for (int kk = 0; kk < 8; ++kk) wreg[gt][kk] = src[kk];
        }
        bia0 = bih[0 * HH + jglob] + bhh[0 * HH + jglob];
        bia1 = bih[1 * HH + jglob] + bhh[1 * HH + jglob];
        bia2 = bih[2 * HH + jglob] + bhh[2 * HH + jglob];
        bia3 = bih[3 * HH + jglob] + bhh[3 * HH + jglob];
        bf0v = baff[0]; bf1v = baff[1];
        waffR = Waff[(size_t)stag * NG + sdim];
        cmi = mask[(size_t)b * TT];
    }

    // ---- prologue phase 0: tg + hk init (rec) | stage A[0] -> buf0 (gemm) ----
    if (tid < 2 * KY) tg[tid >> 5][tid & 31] = tag[tid];
    if (tid < 72) ((float4*)hk)[tid] = make_float4(0.f, 0.f, 0.f, 0.f);
    if (tid >= 512) STAGE_A(0, 0);
    __syncthreads();

    // ---- prologue phase 1: P matrix (rec) | window-0 MFMA + stage A[1] (gemm) ----
    if (tid < 512) {
        int r = tid >> 8, rem = tid & 255, gt = rem >> 6, j2 = rem & 63;
        int row = gt * HH + g * 64 + j2;
        const float4* wr = (const float4*)(Wih + (size_t)row * 800);
        float s = 0.f;
#pragma unroll
        for (int kk = 0; kk < 8; ++kk) {
            float4 v = wr[kk];
            s = fmaf(v.x, tg[r][kk * 4 + 0], s);
            s = fmaf(v.y, tg[r][kk * 4 + 1], s);
            s = fmaf(v.z, tg[r][kk * 4 + 2], s);
            s = fmaf(v.w, tg[r][kk * 4 + 3], s);
        }
        P[r][gt][j2] = s;
    } else {
        for (int ks = 0; ks < 24; ++ks) GEMM_KSTEP(0, ks * 32);
        RING_EPI(0);
        STAGE_A(1, 16);
    }
    __syncthreads();

    // ---- main loop: 512 steps, 2 barriers/step (krec3-identical cadence) ----
    for (int s = 0; s < TT; ++s) {
        const int W = s >> 4, ws = s & 15, p = s & 1, rs = W & 1;
        float mi = 0.f, s2v0 = 0.f, s2v1 = 0.f;

        if (tid < 512) {
            float pv0 = 0.f, pv1 = 0.f, pv2 = 0.f, pv3 = 0.f;
            if (pred >= 0) {
                pv0 = P[pred][0][jh]; pv1 = P[pred][1][jh];
                pv2 = P[pred][2][jh]; pv3 = P[pred][3][jh];
            }
            const int rb = ws * PR;
            const float ga0 = ring[rs][rb + jh] + bia0;
            const float ga1 = ring[rs][rb + 64 + jh] + bia1;
            const float ga2 = ring[rs][rb + 128 + jh] + bia2;
            const float ga3 = ring[rs][rb + 192 + jh] + bia3;
            s2v0 = ring[rs][rb + 256] + bf0v;
            s2v1 = ring[rs][rb + 257] + bf1v;

            float a0 = 0.f, a1 = 0.f, a2 = 0.f, a3 = 0.f;
            const float4* h4 = (const float4*)(hk + kq * 36);
#pragma unroll
            for (int kk = 0; kk < 8; ++kk) {
                float4 hv = h4[kk];
                a0 = fmaf(wreg[0][kk].x, hv.x, a0); a0 = fmaf(wreg[0][kk].y, hv.y, a0);
                a0 = fmaf(wreg[0][kk].z, hv.z, a0); a0 = fmaf(wreg[0][kk].w, hv.w, a0);
                a1 = fmaf(wreg[1][kk].x, hv.x, a1); a1 = fmaf(wreg[1][kk].y, hv.y, a1);
                a1 = fmaf(wreg[1][kk].z, hv.z, a1); a1 = fmaf(wreg[1][kk].w, hv.w, a1);
                a2 = fmaf(wreg[2][kk].x, hv.x, a2); a2 = fmaf(wreg[2][kk].y, hv.y, a2);
                a2 = fmaf(wreg[2][kk].z, hv.z, a2); a2 = fmaf(wreg[2][kk].w, hv.w, a2);
                a3 = fmaf(wreg[3][kk].x, hv.x, a3); a3 = fmaf(wreg[3][kk].y, hv.y, a3);
                a3 = fmaf(wreg[3][kk].z, hv.z, a3); a3 = fmaf(wreg[3][kk].w, hv.w, a3);
            }
            a0 += __shfl_xor(a0, 8, 64); a0 += __shfl_xor(a0, 16, 64); a0 += __shfl_xor(a0, 32, 64);
            a1 += __shfl_xor(a1, 8, 64); a1 += __shfl_xor(a1, 16, 64); a1 += __shfl_xor(a1, 32, 64);
            a2 += __shfl_xor(a2, 8, 64); a2 += __shfl_xor(a2, 16, 64); a2 += __shfl_xor(a2, 32, 64);
            a3 += __shfl_xor(a3, 8, 64); a3 += __shfl_xor(a3, 16, 64); a3 += __shfl_xor(a3, 32, 64);

            float gi = a0 + ga0 + pv0;
            float gf = a1 + ga1 + pv1;
            float gg = a2 + ga2 + pv2;
            float go = a3 + ga3 + pv3;
            float ig = sigf(gi), fg = sigf(gf);
            float g2 = tanhfast(gg), og = sigf(go);
            float cn = fmaf(fg, creg, ig * g2);
            float hn = og * tanhfast(cn);
            mi = cmi;
            creg = cn * mi + creg * (1.f - mi);

            if (kq == 0) {
                unsigned long long wd =
                    ((unsigned long long)__float_as_uint(hn) << 32) | (unsigned)(s + 1);
                __hip_atomic_store(&hbox[((size_t)(p * BB + b) * 4 + g) * 64 + jh], wd,
                                   __ATOMIC_RELAXED, __HIP_MEMORY_SCOPE_AGENT);
                hnS[jglob] = hn;
            }
            if (s + 1 < TT) cmi = mask[(size_t)b * TT + s + 1];

            if (tid < 192) {
                int pg = (g + 1 + (tid >> 6)) & 3, j2 = tid & 63;
                const unsigned long long* wp = &hbox[((size_t)(p * BB + b) * 4 + pg) * 64 + j2];
                unsigned long long wv;
                do {
                    wv = __hip_atomic_load(wp, __ATOMIC_RELAXED, __HIP_MEMORY_SCOPE_AGENT);
                } while ((unsigned)wv != (unsigned)(s + 1));
                hnS[pg * 64 + j2] = __uint_as_float((unsigned)(wv >> 32));
            }
        } else {
            const int Wn = W + 1;
            if (Wn < NW) {
                const int pb = Wn & 1;
                if (ws < 12) {
                    GEMM_KSTEP(pb, ws * 64);
                    GEMM_KSTEP(pb, ws * 64 + 32);
                } else if (ws == 12) {
                    if (W + 2 < NW) STAGE_A((W + 2) & 1, (W + 2) * 16);
                } else if (ws == 15) {
                    RING_EPI(pb);
                }
            }
        }
        __syncthreads();   // B3: hnS complete; ring/A-stage ops ordered

        if (tid < 512) {
            if (tid < HH) {
                int idx = (tid >> 5) * 36 + (tid & 31);
                float hold = hk[idx];
                hk[idx] = hnS[tid] * mi + hold * (1.f - mi);
            }
            float prod = hnS[sdim] * waffR;
            prod += __shfl_xor(prod, 1, 64);
            prod += __shfl_xor(prod, 2, 64);
            prod += __shfl_xor(prod, 4, 64);
            prod += __shfl_xor(prod, 8, 64);
            prod += __shfl_xor(prod, 16, 64);
            if ((lane & 31) == 0) red[w][stag] = prod;
        }
        __syncthreads();   // B4: red + hk complete

        if (tid < 512) {
            float s0 = red[0][0];
            s0 += red[1][0]; s0 += red[2][0]; s0 += red[3][0];
            s0 += red[4][0]; s0 += red[5][0]; s0 += red[6][0]; s0 += red[7][0];
            float s1 = red[0][1];
            s1 += red[1][1]; s1 += red[2][1]; s1 += red[3][1];
            s1 += red[4][1]; s1 += red[5][1]; s1 += red[6][1]; s1 += red[7][1];
            float ts0 = s0 + s2v0, ts1 = s1 + s2v1;
            pred = (ts1 > ts0) ? 1 : 0;
            if (g == 0 && tid == 0) {
                float m = fmaxf(ts0, ts1);
                float lse = m + log1pf(expf(-fabsf(ts0 - ts1)));
                float* op = out + ((size_t)b * TT + s) * 2;
                op[0] = ts0 - lse; op[1] = ts1 - lse;
            }
        }
    }
}

// ---------------------------------------------------------------------------
extern "C" void kernel_launch(void* const* d_in, const int* in_sizes, int n_in,
                              void* d_out, int out_size, void* d_ws, size_t ws_size,
                              hipStream_t stream) {
    (void)in_sizes; (void)n_in; (void)out_size; (void)ws_size;
    const float* sents = (const float*)d_in[0];
    const float* mask  = (const float*)d_in[1];
    const float* Wih   = (const float*)d_in[2];
    const float* Whh   = (const float*)d_in[3];
    const float* bih   = (const float*)d_in[4];
    const float* bhh   = (const float*)d_in[5];
    const float* Waff  = (const float*)d_in[6];
    const float* baff  = (const float*)d_in[7];
    const float* tag   = (const float*)d_in[8];
    float* out = (float*)d_out;

    char* wsp = (char*)d_ws;
    unsigned short* Bsh = (unsigned short*)wsp; wsp += (size_t)1040 * 768 * 2;
    unsigned short* Bsl = (unsigned short*)wsp; wsp += (size_t)1040 * 768 * 2;
    uintptr_t up = ((uintptr_t)wsp + 7) & ~(uintptr_t)7;
    unsigned long long* hbox = (unsigned long long*)up;    // [2][64][4][64]

    kinit<<<dim3(64), 512, 0, stream>>>(hbox);
    kprew<<<dim3(780), 256, 0, stream>>>(Wih, Waff, Bsh, Bsl);
    krecg<<<dim3(256), 768, 0, stream>>>(sents, Bsh, Bsl, Whh, mask, bih, bhh,
                                         baff, out, hbox, Wih, tag, Waff);
}

// Round 9
// 2199.583 us; speedup vs baseline: 1.6678x; 1.6678x over previous
//
#include <hip/hip_runtime.h>
#include <cstdint>
#include <cstddef>

#define TT 512
#define BB 64
#define HH 256
#define NG 1024
#define DI 768
#define KY 32

#define LDP 56   // LDS row pitch (bf16 elems): 112B rows, 2-way-only bank aliasing

typedef __attribute__((ext_vector_type(8))) short bfrag_t;
typedef __attribute__((ext_vector_type(4))) float f4_t;

__device__ __forceinline__ float sigf(float x) {
    return __fdividef(1.f, 1.f + __expf(-x));
}
__device__ __forceinline__ float tanhfast(float x) {
    return fmaf(2.f, sigf(2.f * x), -1.f);
}
__device__ __forceinline__ unsigned short bf_hi(float x) {
    return (unsigned short)(__float_as_uint(x) >> 16);        // truncate to bf16
}
__device__ __forceinline__ float bf_hi_f(float x) {
    return __uint_as_float(__float_as_uint(x) & 0xffff0000u); // exact hi part as f32
}

// ---------------------------------------------------------------------------
// kgemm2 (R0 original, 256 thr): chunk-0 prologue G_pre = A @ B^T + bias.
// ---------------------------------------------------------------------------
__global__ __launch_bounds__(256) void kgemm2(
    const float* __restrict__ sents, const float* __restrict__ Wih,
    const float* __restrict__ bih, const float* __restrict__ bhh,
    float* __restrict__ gpre, int t0)
{
    __shared__ unsigned short Ah[128 * LDP], Al[128 * LDP];
    __shared__ unsigned short Bh[128 * LDP], Bl[128 * LDP];

    const int tid = threadIdx.x;
    const int nb = blockIdx.x;
    const int mb = blockIdx.y;
    const int wv = tid >> 6, lane = tid & 63;
    const int wm = (wv >> 1) * 64, wn = (wv & 1) * 64;
    const int fl = lane & 15, quad = lane >> 4;

    f4_t acc[4][4];
#pragma unroll
    for (int mi = 0; mi < 4; ++mi)
#pragma unroll
        for (int ni = 0; ni < 4; ++ni) acc[mi][ni] = (f4_t)0.f;

    const int sr = tid >> 1, sk = (tid & 1) * 16;
    const int gr = mb * 128 + sr;
    const float* aptr = sents + ((size_t)(gr & 63) * TT + t0 + (gr >> 6)) * DI + sk;
    const float* bptr = Wih + (size_t)(nb * 128 + sr) * 800 + KY + sk;

    for (int k0 = 0; k0 < DI; k0 += 32) {
        float4 av[4], bv[4];
#pragma unroll
        for (int i = 0; i < 4; ++i) {
            av[i] = *(const float4*)(aptr + k0 + i * 4);
            bv[i] = *(const float4*)(bptr + k0 + i * 4);
        }
        __syncthreads();
#pragma unroll
        for (int i = 0; i < 4; ++i) {
            ushort4 h4, l4;
            h4.x = bf_hi(av[i].x); l4.x = bf_hi(av[i].x - bf_hi_f(av[i].x));
            h4.y = bf_hi(av[i].y); l4.y = bf_hi(av[i].y - bf_hi_f(av[i].y));
            h4.z = bf_hi(av[i].z); l4.z = bf_hi(av[i].z - bf_hi_f(av[i].z));
            h4.w = bf_hi(av[i].w); l4.w = bf_hi(av[i].w - bf_hi_f(av[i].w));
            *(ushort4*)&Ah[sr * LDP + sk + i * 4] = h4;
            *(ushort4*)&Al[sr * LDP + sk + i * 4] = l4;
            h4.x = bf_hi(bv[i].x); l4.x = bf_hi(bv[i].x - bf_hi_f(bv[i].x));
            h4.y = bf_hi(bv[i].y); l4.y = bf_hi(bv[i].y - bf_hi_f(bv[i].y));
            h4.z = bf_hi(bv[i].z); l4.z = bf_hi(bv[i].z - bf_hi_f(bv[i].z));
            h4.w = bf_hi(bv[i].w); l4.w = bf_hi(bv[i].w - bf_hi_f(bv[i].w));
            *(ushort4*)&Bh[sr * LDP + sk + i * 4] = h4;
            *(ushort4*)&Bl[sr * LDP + sk + i * 4] = l4;
        }
        __syncthreads();

        bfrag_t ah[4], al2[4], bh[4], bl2[4];
#pragma unroll
        for (int mi = 0; mi < 4; ++mi) {
            int row = wm + mi * 16 + fl;
            ah[mi]  = *(const bfrag_t*)&Ah[row * LDP + quad * 8];
            al2[mi] = *(const bfrag_t*)&Al[row * LDP + quad * 8];
        }
#pragma unroll
        for (int ni = 0; ni < 4; ++ni) {
            int col = wn + ni * 16 + fl;
            bh[ni]  = *(const bfrag_t*)&Bh[col * LDP + quad * 8];
            bl2[ni] = *(const bfrag_t*)&Bl[col * LDP + quad * 8];
        }
#pragma unroll
        for (int mi = 0; mi < 4; ++mi)
#pragma unroll
            for (int ni = 0; ni < 4; ++ni) {
                acc[mi][ni] = __builtin_amdgcn_mfma_f32_16x16x32_bf16(
                    ah[mi], bh[ni], acc[mi][ni], 0, 0, 0);
                acc[mi][ni] = __builtin_amdgcn_mfma_f32_16x16x32_bf16(
                    ah[mi], bl2[ni], acc[mi][ni], 0, 0, 0);
                acc[mi][ni] = __builtin_amdgcn_mfma_f32_16x16x32_bf16(
                    al2[mi], bh[ni], acc[mi][ni], 0, 0, 0);
            }
    }

#pragma unroll
    for (int ni = 0; ni < 4; ++ni) {
        int gcol = nb * 128 + wn + ni * 16 + fl;
        float bias = bih[gcol] + bhh[gcol];
#pragma unroll
        for (int mi = 0; mi < 4; ++mi) {
            int grow = mb * 128 + wm + mi * 16 + quad * 4;
#pragma unroll
            for (int r = 0; r < 4; ++r)
                gpre[(size_t)(grow + r) * NG + gcol] = acc[mi][ni][r] + bias;
        }
    }
}

// ---------------------------------------------------------------------------
// kshi (original, 256 thr): chunk-0 prologue shi.
// ---------------------------------------------------------------------------
__global__ __launch_bounds__(256) void kshi(
    const float* __restrict__ sents, const float* __restrict__ Waff,
    const float* __restrict__ baff, float* __restrict__ shi, int t0)
{
    const int tid = threadIdx.x;
    const int lane = tid & 63;
    const int r = blockIdx.x * 4 + (tid >> 6);
    const int b = r & 63, tl = r >> 6;
    const float* hi = sents + ((size_t)b * TT + t0 + tl) * DI;
    float p0 = 0.f, p1 = 0.f;
#pragma unroll
    for (int kk = 0; kk < 12; ++kk) {
        int k = kk * 64 + lane;
        float x = hi[k];
        p0 = fmaf(x, Waff[HH + k], p0);
        p1 = fmaf(x, Waff[NG + HH + k], p1);
    }
#pragma unroll
    for (int off = 32; off >= 1; off >>= 1) {
        p0 += __shfl_xor(p0, off, 64);
        p1 += __shfl_xor(p1, off, 64);
    }
    if (lane == 0) {
        shi[(size_t)r * 2 + 0] = p0 + baff[0];
        shi[(size_t)r * 2 + 1] = p1 + baff[1];
    }
}

// ---------------------------------------------------------------------------
// init: zero the packed mailbox words
// ---------------------------------------------------------------------------
__global__ void kinit(unsigned long long* __restrict__ hbox) {
    hbox[(size_t)blockIdx.x * 512 + threadIdx.x] = 0ull;
}

// ---------------------------------------------------------------------------
// kstep: INTER-BLOCK fused chunk step.
//   blocks [0,256):        krec3 VERBATIM for chunk c (reads gpreR/shiR)
//   blocks [256,256+Tc*4): 8-wave GEMM for chunk c+1 -> gpreW (idle MFMA pipe,
//                          spare wave slots; no shared barriers with krec)
//   blocks [256+Tc*4,...): kshi for chunk c+1 -> shiW (wave per row)
// Roles are per-BLOCK: krec codegen/barriers untouched (R8's intra-block
// fusion failed on register spill + barrier coupling; this avoids both).
// Cross-chunk ordering via kernel boundaries on the stream; double-buffered
// gpre/shi make concurrent c / c+1 work disjoint.
// ---------------------------------------------------------------------------
__global__ __launch_bounds__(512, 1) void kstep(
    const float* __restrict__ sents,
    const float* __restrict__ Wih, const float* __restrict__ bih,
    const float* __restrict__ bhh, const float* __restrict__ Whh,
    const float* __restrict__ mask, const float* __restrict__ Waff,
    const float* __restrict__ baff, const float* __restrict__ tag,
    float* __restrict__ out,
    const float* __restrict__ gpreR, float* __restrict__ gpreW,
    const float* __restrict__ shiR, float* __restrict__ shiW,
    float* __restrict__ sh, float* __restrict__ sc, int* __restrict__ sp,
    unsigned long long* __restrict__ hbox,
    int t0, int Tc, int first, int doNext)
{
    __shared__ union {
        struct { unsigned short Ah[128 * LDP], Al[128 * LDP],
                                Bh[128 * LDP], Bl[128 * LDP]; } g;   // 57,344 B
        struct { float hk[8 * 36]; float hnS[HH]; float P[2][4][64];
                 float tg[2][KY]; float red[8][2]; } r;              // 4,544 B
    } sm;

    const int tid = threadIdx.x;
    const int gemmBase = 256;
    const int shiBase  = 256 + Tc * 4;

    if (blockIdx.x < 256) {
        // ================== krec3 role (verbatim) ==================
        const int blk = blockIdx.x;
        const int g = blk >> 6, b = blk & 63;
        const int w = tid >> 6, lane = tid & 63;
        const int jl = lane & 7, kq = lane >> 3;
        const int jh = w * 8 + jl;
        const int jglob = g * 64 + jh;

        float4 wreg[4][8];
#pragma unroll
        for (int gt = 0; gt < 4; ++gt) {
            const float4* src = (const float4*)(Whh + (size_t)(gt * HH + jglob) * HH + kq * 32);
#pragma unroll
            for (int kk = 0; kk < 8; ++kk) wreg[gt][kk] = src[kk];
        }

        const int sdim = w * 32 + (lane & 31);
        const int stag = lane >> 5;
        const float waffR = Waff[(size_t)stag * NG + sdim];

        if (tid < 2 * KY) sm.r.tg[tid >> 5][tid & 31] = tag[tid];
        __syncthreads();
        {
            int r = tid >> 8, rem = tid & 255, gt = rem >> 6, j2 = rem & 63;
            int row = gt * HH + g * 64 + j2;
            const float4* wr = (const float4*)(Wih + (size_t)row * 800);
            float s = 0.f;
#pragma unroll
            for (int kk = 0; kk < 8; ++kk) {
                float4 v = wr[kk];
                s = fmaf(v.x, sm.r.tg[r][kk * 4 + 0], s);
                s = fmaf(v.y, sm.r.tg[r][kk * 4 + 1], s);
                s = fmaf(v.z, sm.r.tg[r][kk * 4 + 2], s);
                s = fmaf(v.w, sm.r.tg[r][kk * 4 + 3], s);
            }
            sm.r.P[r][gt][j2] = s;
        }

        float creg; int pred;
        if (first) {
            creg = 0.f; pred = -1;
            if (tid < 72) ((float4*)sm.r.hk)[tid] = make_float4(0.f, 0.f, 0.f, 0.f);
        } else {
            creg = sc[(size_t)b * HH + jglob];
            pred = sp[b];
            if (tid < HH) sm.r.hk[(tid >> 5) * 36 + (tid & 31)] = sh[(size_t)b * HH + tid];
        }
        __syncthreads();

        float cgp0, cgp1, cgp2, cgp3, cmi, cs0, cs1;
        {
            const float* gp = gpreR + (size_t)b * NG;
            cgp0 = gp[0 * HH + jglob]; cgp1 = gp[1 * HH + jglob];
            cgp2 = gp[2 * HH + jglob]; cgp3 = gp[3 * HH + jglob];
            cmi = mask[(size_t)b * TT + t0];
            const float* s2 = shiR + (size_t)b * 2;
            cs0 = s2[0]; cs1 = s2[1];
        }

        for (int tl = 0; tl < Tc; ++tl) {
            const int t = t0 + tl;
            const int p = t & 1;

            float pv0 = 0.f, pv1 = 0.f, pv2 = 0.f, pv3 = 0.f;
            if (pred >= 0) {
                pv0 = sm.r.P[pred][0][jh]; pv1 = sm.r.P[pred][1][jh];
                pv2 = sm.r.P[pred][2][jh]; pv3 = sm.r.P[pred][3][jh];
            }

            float a0 = 0.f, a1 = 0.f, a2 = 0.f, a3 = 0.f;
            const float4* h4 = (const float4*)(sm.r.hk + kq * 36);
#pragma unroll
            for (int kk = 0; kk < 8; ++kk) {
                float4 hv = h4[kk];
                a0 = fmaf(wreg[0][kk].x, hv.x, a0); a0 = fmaf(wreg[0][kk].y, hv.y, a0);
                a0 = fmaf(wreg[0][kk].z, hv.z, a0); a0 = fmaf(wreg[0][kk].w, hv.w, a0);
                a1 = fmaf(wreg[1][kk].x, hv.x, a1); a1 = fmaf(wreg[1][kk].y, hv.y, a1);
                a1 = fmaf(wreg[1][kk].z, hv.z, a1); a1 = fmaf(wreg[1][kk].w, hv.w, a1);
                a2 = fmaf(wreg[2][kk].x, hv.x, a2); a2 = fmaf(wreg[2][kk].y, hv.y, a2);
                a2 = fmaf(wreg[2][kk].z, hv.z, a2); a2 = fmaf(wreg[2][kk].w, hv.w, a2);
                a3 = fmaf(wreg[3][kk].x, hv.x, a3); a3 = fmaf(wreg[3][kk].y, hv.y, a3);
                a3 = fmaf(wreg[3][kk].z, hv.z, a3); a3 = fmaf(wreg[3][kk].w, hv.w, a3);
            }
            a0 += __shfl_xor(a0, 8, 64); a0 += __shfl_xor(a0, 16, 64); a0 += __shfl_xor(a0, 32, 64);
            a1 += __shfl_xor(a1, 8, 64); a1 += __shfl_xor(a1, 16, 64); a1 += __shfl_xor(a1, 32, 64);
            a2 += __shfl_xor(a2, 8, 64); a2 += __shfl_xor(a2, 16, 64); a2 += __shfl_xor(a2, 32, 64);
            a3 += __shfl_xor(a3, 8, 64); a3 += __shfl_xor(a3, 16, 64); a3 += __shfl_xor(a3, 32, 64);

            float gi = a0 + cgp0 + pv0;
            float gf = a1 + cgp1 + pv1;
            float gg = a2 + cgp2 + pv2;
            float go = a3 + cgp3 + pv3;
            float ig = sigf(gi), fg = sigf(gf);
            float g2 = tanhfast(gg), og = sigf(go);
            float cn = fmaf(fg, creg, ig * g2);
            float hn = og * tanhfast(cn);
            float mi = cmi;
            float s2v0 = cs0, s2v1 = cs1;
            creg = cn * mi + creg * (1.f - mi);

            if (kq == 0) {
                unsigned long long wd =
                    ((unsigned long long)__float_as_uint(hn) << 32) | (unsigned)(t + 1);
                __hip_atomic_store(&hbox[((size_t)(p * BB + b) * 4 + g) * 64 + jh], wd,
                                   __ATOMIC_RELAXED, __HIP_MEMORY_SCOPE_AGENT);
                sm.r.hnS[jglob] = hn;
            }

            if (tl + 1 < Tc) {
                const float* gp2 = gpreR + ((size_t)(tl + 1) * BB + b) * NG;
                cgp0 = gp2[0 * HH + jglob]; cgp1 = gp2[1 * HH + jglob];
                cgp2 = gp2[2 * HH + jglob]; cgp3 = gp2[3 * HH + jglob];
                cmi = mask[(size_t)b * TT + t + 1];
                const float* s2n = shiR + ((size_t)(tl + 1) * BB + b) * 2;
                cs0 = s2n[0]; cs1 = s2n[1];
            }

            if (tid < 192) {
                int pg = (g + 1 + (tid >> 6)) & 3, j2 = tid & 63;
                const unsigned long long* wp = &hbox[((size_t)(p * BB + b) * 4 + pg) * 64 + j2];
                unsigned long long wv;
                do {
                    wv = __hip_atomic_load(wp, __ATOMIC_RELAXED, __HIP_MEMORY_SCOPE_AGENT);
                } while ((unsigned)wv != (unsigned)(t + 1));
                sm.r.hnS[pg * 64 + j2] = __uint_as_float((unsigned)(wv >> 32));
            }
            __syncthreads();   // B3

            if (tid < HH) {
                int idx = (tid >> 5) * 36 + (tid & 31);
                float hold = sm.r.hk[idx];
                sm.r.hk[idx] = sm.r.hnS[tid] * mi + hold * (1.f - mi);
            }
            float prod = sm.r.hnS[sdim] * waffR;
            prod += __shfl_xor(prod, 1, 64);
            prod += __shfl_xor(prod, 2, 64);
            prod += __shfl_xor(prod, 4, 64);
            prod += __shfl_xor(prod, 8, 64);
            prod += __shfl_xor(prod, 16, 64);
            if ((lane & 31) == 0) sm.r.red[w][stag] = prod;
            __syncthreads();   // B4

            float s0 = sm.r.red[0][0];
            s0 += sm.r.red[1][0]; s0 += sm.r.red[2][0]; s0 += sm.r.red[3][0];
            s0 += sm.r.red[4][0]; s0 += sm.r.red[5][0]; s0 += sm.r.red[6][0]; s0 += sm.r.red[7][0];
            float s1 = sm.r.red[0][1];
            s1 += sm.r.red[1][1]; s1 += sm.r.red[2][1]; s1 += sm.r.red[3][1];
            s1 += sm.r.red[4][1]; s1 += sm.r.red[5][1]; s1 += sm.r.red[6][1]; s1 += sm.r.red[7][1];
            float ts0 = s0 + s2v0, ts1 = s1 + s2v1;
            pred = (ts1 > ts0) ? 1 : 0;
            if (g == 0 && tid == 0) {
                float m = fmaxf(ts0, ts1);
                float lse = m + log1pf(expf(-fabsf(ts0 - ts1)));
                float* op = out + ((size_t)b * TT + t) * 2;
                op[0] = ts0 - lse; op[1] = ts1 - lse;
            }
        }

        if (kq == 0) {
            sh[(size_t)b * HH + jglob] = sm.r.hk[(jglob >> 5) * 36 + (jglob & 31)];
            sc[(size_t)b * HH + jglob] = creg;
        }
        if (g == 0 && tid == 0) sp[b] = pred;

    } else if (blockIdx.x < shiBase) {
        // ================== GEMM role (chunk c+1, 8 waves) ==================
        if (!doNext) return;
        const int gb = blockIdx.x - gemmBase;
        const int nb = gb & 7, mb = gb >> 3;
        const int t0n = t0 + Tc;
        const int wv = tid >> 6, lane = tid & 63;
        const int wm = (wv >> 2) * 64, wn = (wv & 3) * 32;
        const int fl = lane & 15, quad = lane >> 4;

        f4_t acc[4][2];
#pragma unroll
        for (int mi = 0; mi < 4; ++mi)
#pragma unroll
            for (int ni = 0; ni < 2; ++ni) acc[mi][ni] = (f4_t)0.f;

        const int sr = tid >> 2, sk = (tid & 3) * 8;   // 4 thr/row, 8 floats each
        const int gr = mb * 128 + sr;
        const float* aptr = sents + ((size_t)(gr & 63) * TT + t0n + (gr >> 6)) * DI + sk;
        const float* bptr = Wih + (size_t)(nb * 128 + sr) * 800 + KY + sk;

        for (int k0 = 0; k0 < DI; k0 += 32) {
            float4 av[2], bv[2];
            av[0] = *(const float4*)(aptr + k0);
            av[1] = *(const float4*)(aptr + k0 + 4);
            bv[0] = *(const float4*)(bptr + k0);
            bv[1] = *(const float4*)(bptr + k0 + 4);
            __syncthreads();
#pragma unroll
            for (int i = 0; i < 2; ++i) {
                ushort4 h4, l4;
                h4.x = bf_hi(av[i].x); l4.x = bf_hi(av[i].x - bf_hi_f(av[i].x));
                h4.y = bf_hi(av[i].y); l4.y = bf_hi(av[i].y - bf_hi_f(av[i].y));
                h4.z = bf_hi(av[i].z); l4.z = bf_hi(av[i].z - bf_hi_f(av[i].z));
                h4.w = bf_hi(av[i].w); l4.w = bf_hi(av[i].w - bf_hi_f(av[i].w));
                *(ushort4*)&sm.g.Ah[sr * LDP + sk + i * 4] = h4;
                *(ushort4*)&sm.g.Al[sr * LDP + sk + i * 4] = l4;
                h4.x = bf_hi(bv[i].x); l4.x = bf_hi(bv[i].x - bf_hi_f(bv[i].x));
                h4.y = bf_hi(bv[i].y); l4.y = bf_hi(bv[i].y - bf_hi_f(bv[i].y));
                h4.z = bf_hi(bv[i].z); l4.z = bf_hi(bv[i].z - bf_hi_f(bv[i].z));
                h4.w = bf_hi(bv[i].w); l4.w = bf_hi(bv[i].w - bf_hi_f(bv[i].w));
                *(ushort4*)&sm.g.Bh[sr * LDP + sk + i * 4] = h4;
                *(ushort4*)&sm.g.Bl[sr * LDP + sk + i * 4] = l4;
            }
            __syncthreads();

            bfrag_t ah[4], al2[4], bh[2], bl2[2];
#pragma unroll
            for (int mi = 0; mi < 4; ++mi) {
                int row = wm + mi * 16 + fl;
                ah[mi]  = *(const bfrag_t*)&sm.g.Ah[row * LDP + quad * 8];
                al2[mi] = *(const bfrag_t*)&sm.g.Al[row * LDP + quad * 8];
            }
#pragma unroll
            for (int ni = 0; ni < 2; ++ni) {
                int col = wn + ni * 16 + fl;
                bh[ni]  = *(const bfrag_t*)&sm.g.Bh[col * LDP + quad * 8];
                bl2[ni] = *(const bfrag_t*)&sm.g.Bl[col * LDP + quad * 8];
            }
#pragma unroll
            for (int mi = 0; mi < 4; ++mi)
#pragma unroll
                for (int ni = 0; ni < 2; ++ni) {
                    acc[mi][ni] = __builtin_amdgcn_mfma_f32_16x16x32_bf16(
                        ah[mi], bh[ni], acc[mi][ni], 0, 0, 0);
                    acc[mi][ni] = __builtin_amdgcn_mfma_f32_16x16x32_bf16(
                        ah[mi], bl2[ni], acc[mi][ni], 0, 0, 0);
                    acc[mi][ni] = __builtin_amdgcn_mfma_f32_16x16x32_bf16(
                        al2[mi], bh[ni], acc[mi][ni], 0, 0, 0);
                }
        }

#pragma unroll
        for (int ni = 0; ni < 2; ++ni) {
            int gcol = nb * 128 + wn + ni * 16 + fl;
            float bias = bih[gcol] + bhh[gcol];
#pragma unroll
            for (int mi = 0; mi < 4; ++mi) {
                int grow = mb * 128 + wm + mi * 16 + quad * 4;
#pragma unroll
                for (int r = 0; r < 4; ++r)
                    gpreW[(size_t)(grow + r) * NG + gcol] = acc[mi][ni][r] + bias;
            }
        }

    } else {
        // ================== kshi role (chunk c+1, wave per row) ==================
        if (!doNext) return;
        const int wv = tid >> 6, lane = tid & 63;
        const int r = (blockIdx.x - shiBase) * 8 + wv;
        const int b = r & 63, tl = r >> 6;
        const int t0n = t0 + Tc;
        const float* hi = sents + ((size_t)b * TT + t0n + tl) * DI;
        float p0 = 0.f, p1 = 0.f;
#pragma unroll
        for (int kk = 0; kk < 12; ++kk) {
            int k = kk * 64 + lane;
            float x = hi[k];
            p0 = fmaf(x, Waff[HH + k], p0);
            p1 = fmaf(x, Waff[NG + HH + k], p1);
        }
#pragma unroll
        for (int off = 32; off >= 1; off >>= 1) {
            p0 += __shfl_xor(p0, off, 64);
            p1 += __shfl_xor(p1, off, 64);
        }
        if (lane == 0) {
            shiW[(size_t)r * 2 + 0] = p0 + baff[0];
            shiW[(size_t)r * 2 + 1] = p1 + baff[1];
        }
    }
}

// ---------------------------------------------------------------------------
extern "C" void kernel_launch(void* const* d_in, const int* in_sizes, int n_in,
                              void* d_out, int out_size, void* d_ws, size_t ws_size,
                              hipStream_t stream) {
    (void)in_sizes; (void)n_in; (void)out_size;
    const float* sents = (const float*)d_in[0];
    const float* mask  = (const float*)d_in[1];
    const float* Wih   = (const float*)d_in[2];
    const float* Whh   = (const float*)d_in[3];
    const float* bih   = (const float*)d_in[4];
    const float* bhh   = (const float*)d_in[5];
    const float* Waff  = (const float*)d_in[6];
    const float* baff  = (const float*)d_in[7];
    const float* tag   = (const float*)d_in[8];
    float* out = (float*)d_out;

    const size_t fixed = (size_t)BB * HH * 4 * 2
                       + BB * 4
                       + (size_t)2 * BB * 4 * 64 * 8
                       + 4096;
    int Tc = 8;
    const int cands[4] = {32, 16, 8, 4};
    for (int i = 0; i < 4; ++i) {
        size_t need = 2 * ((size_t)cands[i] * BB * NG * 4 + (size_t)cands[i] * BB * 2 * 4)
                    + fixed;
        if (need <= ws_size) { Tc = cands[i]; break; }
    }

    char* wsp = (char*)d_ws;
    float* gpre0 = (float*)wsp; wsp += (size_t)Tc * BB * NG * 4;
    float* gpre1 = (float*)wsp; wsp += (size_t)Tc * BB * NG * 4;
    float* shi0 = (float*)wsp; wsp += (size_t)Tc * BB * 2 * 4;
    float* shi1 = (float*)wsp; wsp += (size_t)Tc * BB * 2 * 4;
    float* shst = (float*)wsp; wsp += (size_t)BB * HH * 4;
    float* scst = (float*)wsp; wsp += (size_t)BB * HH * 4;
    int*   spst = (int*)wsp;   wsp += BB * 4;
    unsigned long long* hbox = (unsigned long long*)wsp;

    float* gbuf[2] = {gpre0, gpre1};
    float* sbuf[2] = {shi0, shi1};

    kinit<<<dim3(64), 512, 0, stream>>>(hbox);
    kgemm2<<<dim3(8, Tc * 64 / 128), 256, 0, stream>>>(sents, Wih, bih, bhh, gpre0, 0);
    kshi<<<dim3(Tc * 16), 256, 0, stream>>>(sents, Waff, baff, shi0, 0);

    const int nch = TT / Tc;
    const int grid = 256 + Tc * 4 + Tc * 8;
    for (int c = 0; c < nch; ++c) {
        const int t0 = c * Tc;
        kstep<<<dim3(grid), 512, 0, stream>>>(
            sents, Wih, bih, bhh, Whh, mask, Waff, baff, tag, out,
            gbuf[c & 1], gbuf[(c + 1) & 1], sbuf[c & 1], sbuf[(c + 1) & 1],
            shst, scst, spst, hbox,
            t0, Tc, (c == 0) ? 1 : 0, (c + 1 < nch) ? 1 : 0);
    }
}

// Round 10
// 1964.960 us; speedup vs baseline: 1.8669x; 1.1194x over previous
//
#include <hip/hip_runtime.h>
#include <cstdint>
#include <cstddef>

#define TT 512
#define BB 64
#define HH 256
#define NG 1024
#define DI 768
#define KY 32

#define LDP 56   // LDS row pitch (bf16 elems): 112B rows, 2-way-only bank aliasing

typedef __attribute__((ext_vector_type(8))) short bfrag_t;
typedef __attribute__((ext_vector_type(4))) float f4_t;

__device__ __forceinline__ float sigf(float x) {
    return __fdividef(1.f, 1.f + __expf(-x));
}
__device__ __forceinline__ float tanhfast(float x) {
    return fmaf(2.f, sigf(2.f * x), -1.f);
}
__device__ __forceinline__ unsigned short bf_hi(float x) {
    return (unsigned short)(__float_as_uint(x) >> 16);        // truncate to bf16
}
__device__ __forceinline__ float bf_hi_f(float x) {
    return __uint_as_float(__float_as_uint(x) & 0xffff0000u); // exact hi part as f32
}

// ---------------------------------------------------------------------------
// kgemm2: G_pre = A @ B^T + bias via split-bf16 MFMA (3 products: hh+hl+lh).
// (R0-proven version; serial before each krec chunk — R8/R9 proved any
//  overlap with the recurrence inflates the exchange RT 1:1.)
// ---------------------------------------------------------------------------
__global__ __launch_bounds__(256) void kgemm2(
    const float* __restrict__ sents, const float* __restrict__ Wih,
    const float* __restrict__ bih, const float* __restrict__ bhh,
    float* __restrict__ gpre, int t0)
{
    __shared__ unsigned short Ah[128 * LDP], Al[128 * LDP];
    __shared__ unsigned short Bh[128 * LDP], Bl[128 * LDP];

    const int tid = threadIdx.x;
    const int nb = blockIdx.x;            // N tile 0..7
    const int mb = blockIdx.y;            // M tile
    const int wv = tid >> 6, lane = tid & 63;
    const int wm = (wv >> 1) * 64, wn = (wv & 1) * 64;  // wave quadrant
    const int fl = lane & 15, quad = lane >> 4;

    f4_t acc[4][4];
#pragma unroll
    for (int mi = 0; mi < 4; ++mi)
#pragma unroll
        for (int ni = 0; ni < 4; ++ni) acc[mi][ni] = (f4_t)0.f;

    const int sr = tid >> 1, sk = (tid & 1) * 16;
    const int gr = mb * 128 + sr;                       // global A row
    const float* aptr = sents + ((size_t)(gr & 63) * TT + t0 + (gr >> 6)) * DI + sk;
    const float* bptr = Wih + (size_t)(nb * 128 + sr) * 800 + KY + sk;

    for (int k0 = 0; k0 < DI; k0 += 32) {
        float4 av[4], bv[4];
#pragma unroll
        for (int i = 0; i < 4; ++i) {
            av[i] = *(const float4*)(aptr + k0 + i * 4);
            bv[i] = *(const float4*)(bptr + k0 + i * 4);
        }
        __syncthreads();   // previous compute done reading LDS
#pragma unroll
        for (int i = 0; i < 4; ++i) {
            ushort4 h4, l4;
            h4.x = bf_hi(av[i].x); l4.x = bf_hi(av[i].x - bf_hi_f(av[i].x));
            h4.y = bf_hi(av[i].y); l4.y = bf_hi(av[i].y - bf_hi_f(av[i].y));
            h4.z = bf_hi(av[i].z); l4.z = bf_hi(av[i].z - bf_hi_f(av[i].z));
            h4.w = bf_hi(av[i].w); l4.w = bf_hi(av[i].w - bf_hi_f(av[i].w));
            *(ushort4*)&Ah[sr * LDP + sk + i * 4] = h4;
            *(ushort4*)&Al[sr * LDP + sk + i * 4] = l4;
            h4.x = bf_hi(bv[i].x); l4.x = bf_hi(bv[i].x - bf_hi_f(bv[i].x));
            h4.y = bf_hi(bv[i].y); l4.y = bf_hi(bv[i].y - bf_hi_f(bv[i].y));
            h4.z = bf_hi(bv[i].z); l4.z = bf_hi(bv[i].z - bf_hi_f(bv[i].z));
            h4.w = bf_hi(bv[i].w); l4.w = bf_hi(bv[i].w - bf_hi_f(bv[i].w));
            *(ushort4*)&Bh[sr * LDP + sk + i * 4] = h4;
            *(ushort4*)&Bl[sr * LDP + sk + i * 4] = l4;
        }
        __syncthreads();   // tile staged

        bfrag_t ah[4], al2[4], bh[4], bl2[4];
#pragma unroll
        for (int mi = 0; mi < 4; ++mi) {
            int row = wm + mi * 16 + fl;
            ah[mi]  = *(const bfrag_t*)&Ah[row * LDP + quad * 8];
            al2[mi] = *(const bfrag_t*)&Al[row * LDP + quad * 8];
        }
#pragma unroll
        for (int ni = 0; ni < 4; ++ni) {
            int col = wn + ni * 16 + fl;
            bh[ni]  = *(const bfrag_t*)&Bh[col * LDP + quad * 8];
            bl2[ni] = *(const bfrag_t*)&Bl[col * LDP + quad * 8];
        }
#pragma unroll
        for (int mi = 0; mi < 4; ++mi)
#pragma unroll
            for (int ni = 0; ni < 4; ++ni) {
                acc[mi][ni] = __builtin_amdgcn_mfma_f32_16x16x32_bf16(
                    ah[mi], bh[ni], acc[mi][ni], 0, 0, 0);
                acc[mi][ni] = __builtin_amdgcn_mfma_f32_16x16x32_bf16(
                    ah[mi], bl2[ni], acc[mi][ni], 0, 0, 0);
                acc[mi][ni] = __builtin_amdgcn_mfma_f32_16x16x32_bf16(
                    al2[mi], bh[ni], acc[mi][ni], 0, 0, 0);
            }
    }

    // epilogue: C/D layout col=lane&15, row=quad*4+reg (m89-verified)
#pragma unroll
    for (int ni = 0; ni < 4; ++ni) {
        int gcol = nb * 128 + wn + ni * 16 + fl;
        float bias = bih[gcol] + bhh[gcol];
#pragma unroll
        for (int mi = 0; mi < 4; ++mi) {
            int grow = mb * 128 + wm + mi * 16 + quad * 4;
#pragma unroll
            for (int r = 0; r < 4; ++r)
                gpre[(size_t)(grow + r) * NG + gcol] = acc[mi][ni][r] + bias;
        }
    }
}

// ---------------------------------------------------------------------------
// kshi: SHi[t][b][k] = sents[b][t][:] @ Waff[k][256:1024]^T + baff[k]
// Hoisted to ONE launch for all T=512 steps (no recurrence dependence;
// output only 256KB). Replaces 64 per-chunk launches.
// ---------------------------------------------------------------------------
__global__ __launch_bounds__(256) void kshi(
    const float* __restrict__ sents, const float* __restrict__ Waff,
    const float* __restrict__ baff, float* __restrict__ shi)
{
    const int tid = threadIdx.x;
    const int lane = tid & 63;
    const int r = blockIdx.x * 4 + (tid >> 6);   // r = tl*64 + b, tl in [0,512)
    const int b = r & 63, tl = r >> 6;
    const float* hi = sents + ((size_t)b * TT + tl) * DI;
    float p0 = 0.f, p1 = 0.f;
#pragma unroll
    for (int kk = 0; kk < 12; ++kk) {
        int k = kk * 64 + lane;
        float x = hi[k];
        p0 = fmaf(x, Waff[HH + k], p0);
        p1 = fmaf(x, Waff[NG + HH + k], p1);
    }
#pragma unroll
    for (int off = 32; off >= 1; off >>= 1) {
        p0 += __shfl_xor(p0, off, 64);
        p1 += __shfl_xor(p1, off, 64);
    }
    if (lane == 0) {
        shi[(size_t)r * 2 + 0] = p0 + baff[0];
        shi[(size_t)r * 2 + 1] = p1 + baff[1];
    }
}

// ---------------------------------------------------------------------------
// init: zero the packed mailbox words (ws is poisoned 0xAA before every run)
// ---------------------------------------------------------------------------
__global__ void kinit(unsigned long long* __restrict__ hbox) {
    hbox[(size_t)blockIdx.x * 512 + threadIdx.x] = 0ull;
}

// ---------------------------------------------------------------------------
// krec3 (session-best recurrence, UNCHANGED): 4-way split per batch element,
// single-RT packed exchange (relaxed agent atomics, parity double-buffer),
// register prefetch of next-step operands under the poll.
// ---------------------------------------------------------------------------
__global__ __launch_bounds__(512, 1) void krec3(
    const float* __restrict__ gpre,   // [Tc][64][1024]
    const float* __restrict__ shi,    // [Tc][64][2] (chunk-shifted pointer)
    const float* __restrict__ Whh,    // [1024][256]
    const float* __restrict__ mask,   // [64][512]
    float* __restrict__ out,          // [64][512][2]
    float* __restrict__ sh, float* __restrict__ sc, int* __restrict__ sp,
    unsigned long long* __restrict__ hbox,  // [2][64][4][64]
    const float* __restrict__ Wih, const float* __restrict__ tag,
    const float* __restrict__ Waff,
    int t0, int Tc, int first)
{
    const int blk = blockIdx.x;
    const int g = blk >> 6, b = blk & 63;
    const int tid = threadIdx.x;
    const int w = tid >> 6, lane = tid & 63;
    const int jl = lane & 7, kq = lane >> 3;
    const int jh = w * 8 + jl;
    const int jglob = g * 64 + jh;

    __shared__ float hk[8 * 36];
    __shared__ float hnS[HH];
    __shared__ float P[2][4][64];
    __shared__ float tg[2][KY];
    __shared__ float red[8][2];

    float4 wreg[4][8];
#pragma unroll
    for (int gt = 0; gt < 4; ++gt) {
        const float4* src = (const float4*)(Whh + (size_t)(gt * HH + jglob) * HH + kq * 32);
#pragma unroll
        for (int kk = 0; kk < 8; ++kk) wreg[gt][kk] = src[kk];
    }

    const int sdim = w * 32 + (lane & 31);
    const int stag = lane >> 5;
    const float waffR = Waff[(size_t)stag * NG + sdim];

    if (tid < 2 * KY) tg[tid >> 5][tid & 31] = tag[tid];
    __syncthreads();
    {
        int r = tid >> 8, rem = tid & 255, gt = rem >> 6, j2 = rem & 63;
        int row = gt * HH + g * 64 + j2;
        const float4* wr = (const float4*)(Wih + (size_t)row * 800);
        float s = 0.f;
#pragma unroll
        for (int kk = 0; kk < 8; ++kk) {
            float4 v = wr[kk];
            s = fmaf(v.x, tg[r][kk * 4 + 0], s);
            s = fmaf(v.y, tg[r][kk * 4 + 1], s);
            s = fmaf(v.z, tg[r][kk * 4 + 2], s);
            s = fmaf(v.w, tg[r][kk * 4 + 3], s);
        }
        P[r][gt][j2] = s;
    }

    float creg; int pred;
    if (first) {
        creg = 0.f; pred = -1;
        if (tid < 72) ((float4*)hk)[tid] = make_float4(0.f, 0.f, 0.f, 0.f);
    } else {
        creg = sc[(size_t)b * HH + jglob];
        pred = sp[b];
        if (tid < HH) hk[(tid >> 5) * 36 + (tid & 31)] = sh[(size_t)b * HH + tid];
    }
    __syncthreads();

    // current-step operand registers (prefetched)
    float cgp0, cgp1, cgp2, cgp3, cmi, cs0, cs1;
    {
        const float* gp = gpre + ((size_t)0 * BB + b) * NG;
        cgp0 = gp[0 * HH + jglob]; cgp1 = gp[1 * HH + jglob];
        cgp2 = gp[2 * HH + jglob]; cgp3 = gp[3 * HH + jglob];
        cmi = mask[(size_t)b * TT + t0];
        const float* s2 = shi + ((size_t)0 * BB + b) * 2;
        cs0 = s2[0]; cs1 = s2[1];
    }

    for (int tl = 0; tl < Tc; ++tl) {
        const int t = t0 + tl;
        const int p = t & 1;

        float pv0 = 0.f, pv1 = 0.f, pv2 = 0.f, pv3 = 0.f;
        if (pred >= 0) {
            pv0 = P[pred][0][jh]; pv1 = P[pred][1][jh];
            pv2 = P[pred][2][jh]; pv3 = P[pred][3][jh];
        }

        float a0 = 0.f, a1 = 0.f, a2 = 0.f, a3 = 0.f;
        const float4* h4 = (const float4*)(hk + kq * 36);
#pragma unroll
        for (int kk = 0; kk < 8; ++kk) {
            float4 hv = h4[kk];
            a0 = fmaf(wreg[0][kk].x, hv.x, a0); a0 = fmaf(wreg[0][kk].y, hv.y, a0);
            a0 = fmaf(wreg[0][kk].z, hv.z, a0); a0 = fmaf(wreg[0][kk].w, hv.w, a0);
            a1 = fmaf(wreg[1][kk].x, hv.x, a1); a1 = fmaf(wreg[1][kk].y, hv.y, a1);
            a1 = fmaf(wreg[1][kk].z, hv.z, a1); a1 = fmaf(wreg[1][kk].w, hv.w, a1);
            a2 = fmaf(wreg[2][kk].x, hv.x, a2); a2 = fmaf(wreg[2][kk].y, hv.y, a2);
            a2 = fmaf(wreg[2][kk].z, hv.z, a2); a2 = fmaf(wreg[2][kk].w, hv.w, a2);
            a3 = fmaf(wreg[3][kk].x, hv.x, a3); a3 = fmaf(wreg[3][kk].y, hv.y, a3);
            a3 = fmaf(wreg[3][kk].z, hv.z, a3); a3 = fmaf(wreg[3][kk].w, hv.w, a3);
        }
        a0 += __shfl_xor(a0, 8, 64); a0 += __shfl_xor(a0, 16, 64); a0 += __shfl_xor(a0, 32, 64);
        a1 += __shfl_xor(a1, 8, 64); a1 += __shfl_xor(a1, 16, 64); a1 += __shfl_xor(a1, 32, 64);
        a2 += __shfl_xor(a2, 8, 64); a2 += __shfl_xor(a2, 16, 64); a2 += __shfl_xor(a2, 32, 64);
        a3 += __shfl_xor(a3, 8, 64); a3 += __shfl_xor(a3, 16, 64); a3 += __shfl_xor(a3, 32, 64);

        float gi = a0 + cgp0 + pv0;
        float gf = a1 + cgp1 + pv1;
        float gg = a2 + cgp2 + pv2;
        float go = a3 + cgp3 + pv3;
        float ig = sigf(gi), fg = sigf(gf);
        float g2 = tanhfast(gg), og = sigf(go);
        float cn = fmaf(fg, creg, ig * g2);
        float hn = og * tanhfast(cn);
        float mi = cmi;
        float s2v0 = cs0, s2v1 = cs1;
        creg = cn * mi + creg * (1.f - mi);

        // publish own slice (one packed 8B word per dim, no fence)
        if (kq == 0) {
            unsigned long long wd =
                ((unsigned long long)__float_as_uint(hn) << 32) | (unsigned)(t + 1);
            __hip_atomic_store(&hbox[((size_t)(p * BB + b) * 4 + g) * 64 + jh], wd,
                               __ATOMIC_RELAXED, __HIP_MEMORY_SCOPE_AGENT);
            hnS[jglob] = hn;
        }

        // ---- prefetch next step's operands NOW (hidden under the poll) ----
        if (tl + 1 < Tc) {
            const float* gp2 = gpre + ((size_t)(tl + 1) * BB + b) * NG;
            cgp0 = gp2[0 * HH + jglob]; cgp1 = gp2[1 * HH + jglob];
            cgp2 = gp2[2 * HH + jglob]; cgp3 = gp2[3 * HH + jglob];
            cmi = mask[(size_t)b * TT + t + 1];
            const float* s2n = shi + ((size_t)(tl + 1) * BB + b) * 2;
            cs0 = s2n[0]; cs1 = s2n[1];
        }

        // gather partner slices
        if (tid < 192) {
            int pg = (g + 1 + (tid >> 6)) & 3, j2 = tid & 63;
            const unsigned long long* wp = &hbox[((size_t)(p * BB + b) * 4 + pg) * 64 + j2];
            unsigned long long wv;
            do {
                wv = __hip_atomic_load(wp, __ATOMIC_RELAXED, __HIP_MEMORY_SCOPE_AGENT);
            } while ((unsigned)wv != (unsigned)(t + 1));
            hnS[pg * 64 + j2] = __uint_as_float((unsigned)(wv >> 32));
        }
        __syncthreads();   // B3: hnS complete; hk reads of this step done

        if (tid < HH) {
            int idx = (tid >> 5) * 36 + (tid & 31);
            float hold = hk[idx];
            hk[idx] = hnS[tid] * mi + hold * (1.f - mi);
        }
        float prod = hnS[sdim] * waffR;
        prod += __shfl_xor(prod, 1, 64);
        prod += __shfl_xor(prod, 2, 64);
        prod += __shfl_xor(prod, 4, 64);
        prod += __shfl_xor(prod, 8, 64);
        prod += __shfl_xor(prod, 16, 64);
        if ((lane & 31) == 0) red[w][stag] = prod;
        __syncthreads();   // B4: red + hk complete

        float s0 = red[0][0];
        s0 += red[1][0]; s0 += red[2][0]; s0 += red[3][0];
        s0 += red[4][0]; s0 += red[5][0]; s0 += red[6][0]; s0 += red[7][0];
        float s1 = red[0][1];
        s1 += red[1][1]; s1 += red[2][1]; s1 += red[3][1];
        s1 += red[4][1]; s1 += red[5][1]; s1 += red[6][1]; s1 += red[7][1];
        float ts0 = s0 + s2v0, ts1 = s1 + s2v1;
        pred = (ts1 > ts0) ? 1 : 0;
        if (g == 0 && tid == 0) {
            float m = fmaxf(ts0, ts1);
            float lse = m + log1pf(expf(-fabsf(ts0 - ts1)));
            float* op = out + ((size_t)b * TT + t) * 2;
            op[0] = ts0 - lse; op[1] = ts1 - lse;
        }
    }

    if (kq == 0) {
        sh[(size_t)b * HH + jglob] = hk[(jglob >> 5) * 36 + (jglob & 31)];
        sc[(size_t)b * HH + jglob] = creg;
    }
    if (g == 0 && tid == 0) sp[b] = pred;
}

// ---------------------------------------------------------------------------
extern "C" void kernel_launch(void* const* d_in, const int* in_sizes, int n_in,
                              void* d_out, int out_size, void* d_ws, size_t ws_size,
                              hipStream_t stream) {
    (void)in_sizes; (void)n_in; (void)out_size;
    const float* sents = (const float*)d_in[0];
    const float* mask  = (const float*)d_in[1];
    const float* Wih   = (const float*)d_in[2];
    const float* Whh   = (const float*)d_in[3];
    const float* bih   = (const float*)d_in[4];
    const float* bhh   = (const float*)d_in[5];
    const float* Waff  = (const float*)d_in[6];
    const float* baff  = (const float*)d_in[7];
    const float* tag   = (const float*)d_in[8];
    float* out = (float*)d_out;

    const size_t shibytes = (size_t)TT * BB * 2 * 4;   // full-T shi: 256KB
    const size_t fixed = (size_t)BB * HH * 4 * 2       // sh, sc
                       + BB * 4                        // sp
                       + (size_t)2 * BB * 4 * 64 * 8   // hbox
                       + shibytes
                       + 4096;
    int Tc = 8;
    const int cands[3] = {32, 16, 8};
    for (int i = 0; i < 3; ++i) {
        size_t need = (size_t)cands[i] * BB * NG * 4 + fixed;
        if (need <= ws_size) { Tc = cands[i]; break; }
    }

    char* wsp = (char*)d_ws;
    float* gpre = (float*)wsp; wsp += (size_t)Tc * BB * NG * 4;
    float* shiw = (float*)wsp; wsp += shibytes;
    float* shst = (float*)wsp; wsp += (size_t)BB * HH * 4;
    float* scst = (float*)wsp; wsp += (size_t)BB * HH * 4;
    int*   spst = (int*)wsp;   wsp += BB * 4;
    unsigned long long* hbox = (unsigned long long*)wsp;

    kinit<<<dim3(64), 512, 0, stream>>>(hbox);
    kshi<<<dim3(TT * 16), 256, 0, stream>>>(sents, Waff, baff, shiw);

    const int nch = TT / Tc;
    for (int c = 0; c < nch; ++c) {
        const int t0 = c * Tc;
        kgemm2<<<dim3(8, Tc * 64 / 128), 256, 0, stream>>>(sents, Wih, bih, bhh, gpre, t0);
        krec3<<<dim3(256), 512, 0, stream>>>(gpre, shiw + (size_t)t0 * BB * 2,
                                             Whh, mask, out,
                                             shst, scst, spst, hbox,
                                             Wih, tag, Waff, t0, Tc, (c == 0) ? 1 : 0);
    }
}